// Round 5
// baseline (1502.893 us; speedup 1.0000x reference)
//
#include <hip/hip_runtime.h>

#define BATCH 8
#define C     64
#define H     128
#define WD    128
#define C3    192
#define HW    (H*WD)
#define PW    130         // padded H/W for conv input
#define HGX   66          // conv half-stage width in pixels (64 + 2 halo)
#define HBUF  (4*HGX*64)  // conv half-stage buffer: 4 rows x 66 gx x 64 c (shorts)

// attn LDS tiles: 64 rows x 64 cols, granule-XOR swizzled, no pad.
#define SWZ(r) ((((r) & 7) ^ (((r) >> 3) & 6)))

typedef __attribute__((ext_vector_type(8))) short short8;
typedef __attribute__((ext_vector_type(4))) float f32x4;
typedef unsigned short ushort_t;

__device__ __forceinline__ unsigned short f2bf(float f) {
    unsigned u = __builtin_bit_cast(unsigned, f);
    u += 0x7fffu + ((u >> 16) & 1u);
    return (unsigned short)(u >> 16);
}
__device__ __forceinline__ int pack2(unsigned short lo, unsigned short hi) {
    return (int)(((unsigned)hi << 16) | (unsigned)lo);
}

// ===========================================================================
// compose_kernel: fold Wx into Wx1/Wx2; pack 5 weight mats to bf16 + biases.
// ===========================================================================
__global__ __launch_bounds__(64) void compose_kernel(
    const float* __restrict__ Wx,  const float* __restrict__ bx,
    const float* __restrict__ Wx1, const float* __restrict__ bx1,
    const float* __restrict__ Wx2, const float* __restrict__ bx2,
    const float* __restrict__ Wxf, const float* __restrict__ bxf,
    const float* __restrict__ Wxr, const float* __restrict__ bxr,
    ushort_t* __restrict__ Wall, float* __restrict__ ball)
{
    int o = blockIdx.x;      // 0..63
    int c = threadIdx.x;     // 0..63
    Wall[0*4096 + o*64 + c] = f2bf(Wx [o*64 + c]);
    Wall[3*4096 + o*64 + c] = f2bf(Wxf[o*64 + c]);
    Wall[4*4096 + o*64 + c] = f2bf(Wxr[o*64 + c]);
    float a1 = 0.f, a2 = 0.f;
    for (int k = 0; k < 64; ++k) {
        float wc = Wx[k*64 + c];          // coalesced across lanes
        a1 += Wx1[o*64 + k] * wc;         // scalar broadcast
        a2 += Wx2[o*64 + k] * wc;
    }
    Wall[1*4096 + o*64 + c] = f2bf(a1);
    Wall[2*4096 + o*64 + c] = f2bf(a2);
    float t1 = Wx1[o*64 + c] * bx[c];
    float t2 = Wx2[o*64 + c] * bx[c];
    for (int off = 32; off; off >>= 1) {
        t1 += __shfl_down(t1, off);
        t2 += __shfl_down(t2, off);
    }
    if (c == 0) {
        ball[0*64 + o] = bx[o];
        ball[1*64 + o] = bx1[o] + t1;
        ball[2*64 + o] = bx2[o] + t2;
        ball[3*64 + o] = bxf[o];
        ball[4*64 + o] = bxr[o];
    }
}

// ===========================================================================
// prep v4: split into 3 independent block families (x / xf / xr) to shorten
// the serial critical path. which=0 also zeroes feat+xcl halos.
// ===========================================================================
__global__ __launch_bounds__(256) void prep_kernel(
    const float* __restrict__ x, const float* __restrict__ xf,
    const float* __restrict__ xr,
    ushort_t* __restrict__ xcl, ushort_t* __restrict__ feat,
    ushort_t* __restrict__ xfT, ushort_t* __restrict__ xrT)
{
    const int which = blockIdx.x / (BATCH*PW);
    const int r = blockIdx.x % (BATCH*PW);
    const int b = r / PW, py = r % PW;
    const int t = threadIdx.x;
    const size_t prow = ((size_t)b*PW + py)*PW;   // pixel row base

    __shared__ ushort_t sx[128*72];

    if (which == 0) {
        if (py == 0 || py == PW-1) {
            int4 z = make_int4(0,0,0,0);
            for (int j = t; j < PW*128/8; j += 256) ((int4*)(feat + prow*128))[j] = z;
            for (int j = t; j < PW*64/8;  j += 256) ((int4*)(xcl  + prow*64 ))[j] = z;
            return;
        }
        if (t < 48) {
            int4 z = make_int4(0,0,0,0);
            if (t < 32) {
                int side = t >> 4, seg = t & 15;
                *(int4*)(feat + (prow + (side ? PW-1 : 0))*128 + seg*8) = z;
            } else {
                int u = t - 32, side = u >> 3, seg = u & 7;
                *(int4*)(xcl + (prow + (side ? PW-1 : 0))*64 + seg*8) = z;
            }
        }
        const int y = py - 1;
        for (int k = t; k < 64*128; k += 256) {
            int c = k >> 7, xx = k & 127;
            sx[xx*72 + c] = f2bf(x[((size_t)b*C + c)*HW + (size_t)y*WD + xx]);
        }
        __syncthreads();
        for (int j = t; j < 128*8; j += 256) {
            int xx = j >> 3, seg = j & 7;
            *(int4*)(xcl + (prow + xx + 1)*64 + seg*8) = *(const int4*)(sx + xx*72 + seg*8);
        }
        return;
    }

    if (py == 0 || py == PW-1) return;
    const int y = py - 1;
    const float* src = (which == 1) ? xf : xr;
    ushort_t* dstT   = (which == 1) ? xfT : xrT;
    for (int k = t; k < 64*128; k += 256) {
        int c = k >> 7, xx = k & 127;
        sx[xx*72 + c] = f2bf(src[((size_t)b*C + c)*HW + (size_t)y*WD + xx]);
    }
    __syncthreads();
    for (int j = t; j < 128*8; j += 256) {
        int xx = j >> 3, seg = j & 7;
        *(int4*)(dstT + (((size_t)b*128 + y)*128 + xx)*64 + seg*8) = *(const int4*)(sx + xx*72 + seg*8);
    }
}

// ===========================================================================
// attn_mfma v3: one block per (b,h), 256 threads = 4 waves. (unchanged)
// ===========================================================================
__global__ __launch_bounds__(256, 3) void attn_mfma(
    const ushort_t* __restrict__ xcl, const ushort_t* __restrict__ xfT,
    const ushort_t* __restrict__ xrT,
    const ushort_t* __restrict__ Wall, const float* __restrict__ ball,
    ushort_t* __restrict__ feat)
{
    __shared__ ushort_t lds[6*4096];
    ushort_t* P = lds;            // buffer roles rotate; see phase comments
    ushort_t* Q = lds + 4096;
    ushort_t* U = lds + 2*4096;
    ushort_t* R = lds + 3*4096;
    ushort_t* V = lds + 4*4096;
    ushort_t* T = lds + 5*4096;

    const int t = threadIdx.x;
    const int wv = t >> 6, lane = t & 63, m = lane & 15, quad = lane >> 4;
    const int b = blockIdx.x >> 7, h = blockIdx.x & 127;
    const size_t rowbase = ((size_t)b*PW + h + 1)*PW;          // xcl/feat pixels
    const ushort_t* xrow  = xcl + (rowbase + 1)*64;            // interior pixel 0
    const ushort_t* xfrow = xfT + ((size_t)b*128 + h)*128*64;
    const ushort_t* xrrow = xrT + ((size_t)b*128 + h)*128*64;

    // stage a 64-pixel x 64-ch bf16 tile (pixel stride 64 shorts) into LDS
    auto stageT = [&](const ushort_t* base, ushort_t* dst) {
#pragma unroll
        for (int it = 0; it < 2; ++it) {
            int slot = it*256 + t;               // 512 slots of 16B
            int w = slot >> 3, seg = slot & 7;
            *(int4*)(dst + w*64 + ((seg ^ SWZ(w)) << 3)) =
                *(const int4*)(base + w*64 + seg*8);
        }
    };
    auto projB = [&](const ushort_t* src, const ushort_t* W, const float* bias,
                     ushort_t* dst) {
        int arow = wv*16 + m;
        int sa = SWZ(arow);
#pragma unroll
        for (int nt = 0; nt < 4; ++nt) {
            f32x4 acc = {0.f,0.f,0.f,0.f};
#pragma unroll
            for (int k = 0; k < 2; ++k) {
                short8 a  = *(const short8*)(src + arow*64 + (((4*k+quad) ^ sa) << 3));
                short8 bb = *(const short8*)(W   + (nt*16 + m)*64  + k*32 + quad*8);
                acc = __builtin_amdgcn_mfma_f32_16x16x32_bf16(a, bb, acc, 0,0,0);
            }
            float bo = bias[nt*16 + m];
            int o = nt*16 + m, w0 = wv*16 + quad*4;
            int base = o*64 + (((w0 >> 3) ^ SWZ(o)) << 3) + (w0 & 7);
            *(int*)(dst + base)     = pack2(f2bf(acc[0]+bo), f2bf(acc[1]+bo));
            *(int*)(dst + base + 2) = pack2(f2bf(acc[2]+bo), f2bf(acc[3]+bo));
        }
    };
    auto projA = [&](const ushort_t* src, const ushort_t* W, const float* bias,
                     ushort_t* dstT) {
        float b4[4];
#pragma unroll
        for (int r = 0; r < 4; ++r) b4[r] = bias[wv*16 + quad*4 + r];
#pragma unroll
        for (int nt = 0; nt < 4; ++nt) {
            f32x4 acc = {0.f,0.f,0.f,0.f};
            int brow = nt*16 + m;
            int sb = SWZ(brow);
#pragma unroll
            for (int k = 0; k < 2; ++k) {
                short8 a  = *(const short8*)(W   + (wv*16 + m)*64  + k*32 + quad*8);
                short8 bb = *(const short8*)(src + brow*64 + (((4*k+quad) ^ sb) << 3));
                acc = __builtin_amdgcn_mfma_f32_16x16x32_bf16(a, bb, acc, 0,0,0);
            }
            int w = nt*16 + m, o0 = wv*16 + quad*4;
            int base = w*64 + (((o0 >> 3) ^ SWZ(w)) << 3) + (o0 & 7);
            *(int*)(dstT + base)     = pack2(f2bf(acc[0]+b4[0]), f2bf(acc[1]+b4[1]));
            *(int*)(dstT + base + 2) = pack2(f2bf(acc[2]+b4[2]), f2bf(acc[3]+b4[3]));
        }
    };
    auto scoreStep = [&](const ushort_t* A, const ushort_t* B, f32x4* sc) {
        int arow = wv*16 + m;
        int sa = SWZ(arow);
#pragma unroll
        for (int nt = 0; nt < 4; ++nt) {
            int brow = nt*16 + m;
            int sb = SWZ(brow);
#pragma unroll
            for (int k = 0; k < 2; ++k) {
                short8 a  = *(const short8*)(A + arow*64 + (((4*k+quad) ^ sa) << 3));
                short8 bb = *(const short8*)(B + brow*64 + (((4*k+quad) ^ sb) << 3));
                sc[nt] = __builtin_amdgcn_mfma_f32_16x16x32_bf16(a, bb, sc[nt], 0,0,0);
            }
        }
    };
    auto scoreDump = [&](const f32x4* sc, ushort_t* dst) {
        int c0 = wv*16 + quad*4;
#pragma unroll
        for (int nt = 0; nt < 4; ++nt) {
            int d = nt*16 + m;
            int gd = d >> 3, dl = d & 7;
#pragma unroll
            for (int r = 0; r < 4; ++r) {
                int row = c0 + r;
                dst[row*64 + ((gd ^ SWZ(row)) << 3) + dl] = f2bf(sc[nt][r]);
            }
        }
    };
    auto featF = [&](const ushort_t* Sc, const ushort_t* XpT, ushort_t* stg) {
        int arow = wv*16 + m;
        int sa = SWZ(arow);
#pragma unroll
        for (int nt = 0; nt < 4; ++nt) {
            f32x4 acc = {0.f,0.f,0.f,0.f};
            int brow = nt*16 + m;
            int sb = SWZ(brow);
#pragma unroll
            for (int k = 0; k < 2; ++k) {
                short8 a  = *(const short8*)(Sc  + arow*64 + (((4*k+quad) ^ sa) << 3));
                short8 bb = *(const short8*)(XpT + brow*64 + (((4*k+quad) ^ sb) << 3));
                acc = __builtin_amdgcn_mfma_f32_16x16x32_bf16(a, bb, acc, 0,0,0);
            }
            int w = nt*16 + m, c0 = wv*16 + quad*4;
            int base = w*64 + (((c0 >> 3) ^ SWZ(w)) << 3) + (c0 & 7);
            *(int*)(stg + base)     = pack2(f2bf(acc[0]), f2bf(acc[1]));
            *(int*)(stg + base + 2) = pack2(f2bf(acc[2]), f2bf(acc[3]));
        }
    };
    auto emitPair = [&](const ushort_t* O1, const ushort_t* O2, int wc) {
#pragma unroll
        for (int it = 0; it < 4; ++it) {
            int j = (it & 1)*256 + t;
            const ushort_t* S = (it < 2) ? O1 : O2;
            int half = (it < 2) ? 0 : 64;
            int row = j >> 3, seg = j & 7;
            int4 v = *(const int4*)(S + row*64 + ((seg ^ SWZ(row)) << 3));
            *(int4*)(feat + (rowbase + wc + 1 + row)*128 + half + seg*8) = v;
        }
    };

    const ushort_t* W0 = Wall;            const float* b0 = ball;
    const ushort_t* W1 = Wall + 4096;     const float* b1 = ball + 64;
    const ushort_t* W2 = Wall + 2*4096;   const float* b2 = ball + 128;
    const ushort_t* W3 = Wall + 3*4096;   const float* b3 = ball + 192;
    const ushort_t* W4 = Wall + 4*4096;   const float* b4 = ball + 256;

    f32x4 sc1[4], sc2[4];
#pragma unroll
    for (int i = 0; i < 4; ++i) { sc1[i] = (f32x4){0,0,0,0}; sc2[i] = (f32x4){0,0,0,0}; }

    // ================= loop 1: scores (3 phases/chunk) =================
    stageT(xrow, P); stageT(xfrow, Q); stageT(xrrow, U);
    __syncthreads();
    // chunk 0: x=P, xf=Q, xr=U
    projB(P, W1, b1, R);  projB(P, W2, b2, V);  projB(Q, W3, b3, T);
    __syncthreads();
    scoreStep(R, T, sc1); projB(U, W4, b4, Q);
    __syncthreads();
    scoreStep(V, Q, sc2);
    stageT(xrow + 64*64, P); stageT(xfrow + 64*64, T); stageT(xrrow + 64*64, U);
    __syncthreads();
    // chunk 1: x=P, xf=T, xr=U
    projB(P, W1, b1, R);  projB(P, W2, b2, V);  projB(T, W3, b3, Q);
    __syncthreads();
    scoreStep(R, Q, sc1); projB(U, W4, b4, T);
    __syncthreads();
    scoreStep(V, T, sc2);
    stageT(xrow, P);                       // x chunk0 again for loop 2
    __syncthreads();

    // ================= loop 2: features (3 phases/chunk) =================
    scoreDump(sc1, Q);  scoreDump(sc2, U);
    __syncthreads();
    // chunk 0: X=P -> XT=R; outputs P,T; prefetch x64 -> V
    projA(P, W0, b0, R);
    __syncthreads();
    featF(Q, R, P);  featF(U, R, T);  stageT(xrow + 64*64, V);
    __syncthreads();
    emitPair(P, T, 0);
    __syncthreads();
    // chunk 1: X=V -> XT=R; outputs V,T
    projA(V, W0, b0, R);
    __syncthreads();
    featF(Q, R, V);  featF(U, R, T);
    __syncthreads();
    emitPair(V, T, 64);
}

// ===========================================================================
// weight pack for conv: W_msa -> Wpack[otile][tap*6+icc][lane][8] bf16.
// ===========================================================================
__global__ __launch_bounds__(256) void pack_kernel(const float* __restrict__ W,
                                                   ushort_t* __restrict__ Wpk)
{
    int k = blockIdx.x*256 + threadIdx.x;
    if (k >= 12*54*64) return;
    int lane = k & 63, os = k >> 6;
    int otile = os / 54, s = os % 54;
    int tap = s / 6, icc = s % 6;
    int o   = otile*16 + (lane & 15);
    int ic0 = icc*32 + (lane >> 4)*8;
    ushort_t v[8];
#pragma unroll
    for (int j = 0; j < 8; ++j)
        v[j] = f2bf(W[(size_t)(o*C3 + ic0 + j)*9 + tap]);
    *(int4*)(Wpk + (size_t)k*8) = *(const int4*)v;
}

// ===========================================================================
// conv v6: producer-consumer implicit-GEMM bf16 MFMA, half-width stages.
// Block = (b, y-pair), 512 threads = 8 waves: 6 compute + 2 produce.
// Stage = (ch, xh): 4 rows x 66 gx x 64 c = 33,792 B; dbuf = 67,584 B
// -> 2 blocks/CU (vs v4's 1): barrier drains + ds_read latency overlap
// across blocks. Same swizzle/read geometry as v4 (0 bank conflicts),
// same per-acc K order (bit-identical output). 6 stages of 288 MFMA/wave.
// Epilogue: 96-channel sOut passes (50.7 KB fits the smaller LDS).
// ===========================================================================
__global__ __launch_bounds__(512, 4) void conv_mfma(
    const ushort_t* __restrict__ feat, const ushort_t* __restrict__ xcl,
    const ushort_t* __restrict__ Wpk,
    const float* __restrict__ bias, const float* __restrict__ gamma,
    const float* __restrict__ beta, const float* __restrict__ mean,
    const float* __restrict__ var,  float* __restrict__ out)
{
    __shared__ ushort_t sA[2*HBUF];            // 67,584 B

    const int t = threadIdx.x;
    const int wv = t >> 6, lane = t & 63;
    const int m = lane & 15, quad = lane >> 4;
    const int b  = blockIdx.x >> 6, y0 = (blockIdx.x & 63)*2;
    const int yi = wv & 1, og = wv >> 1;       // compute waves: og 0..2

    f32x4 acc[32];                              // [j][xt] -> acc[j*8+xt]
#pragma unroll
    for (int i = 0; i < 32; ++i) acc[i] = (f32x4){0.f,0.f,0.f,0.f};

    // ---- producer: stage half-chunk (ch,xh): 2112 16B slots, 128 lanes ----
    auto produce = [&](int ch, int xh, int bufi) {
        ushort_t* dst = sA + bufi*HBUF;
        const ushort_t* base = (ch < 2) ? feat : xcl;
        const int ps = (ch < 2) ? 128 : 64;
        const int co = (ch == 1) ? 64 : 0;
        const int pt = t - 384;                // wave 6 -> 0..63, wave 7 -> 64..127
        for (int i = 0; i < 16; ++i) {
            int sl = i*128 + pt;
            int wi = sl & 7, rowgx = sl >> 3;
            int row = rowgx / HGX, gxl = rowgx - row*HGX;
            int wl = wi ^ (gxl & 7);           // granule swizzle (global side)
            const ushort_t* g = base + (((size_t)b*PW + y0 + row)*PW + xh*64 + gxl)*ps
                                     + co + wl*8;
            __builtin_amdgcn_global_load_lds(
                (const __attribute__((address_space(1))) unsigned int*)g,
                (__attribute__((address_space(3))) unsigned int*)(dst + (size_t)sl*8),
                16, 0, 0);
        }
        if (pt < 64) {
            int sl = 2048 + pt;
            int wi = sl & 7, rowgx = sl >> 3;
            int row = rowgx / HGX, gxl = rowgx - row*HGX;
            int wl = wi ^ (gxl & 7);
            const ushort_t* g = base + (((size_t)b*PW + y0 + row)*PW + xh*64 + gxl)*ps
                                     + co + wl*8;
            __builtin_amdgcn_global_load_lds(
                (const __attribute__((address_space(1))) unsigned int*)g,
                (__attribute__((address_space(3))) unsigned int*)(dst + (size_t)sl*8),
                16, 0, 0);
        }
    };

    // ---- consumer: one half-stage = 9 taps x 4 xtl x 2 k x 4 o-tiles ----
    auto compute = [&](int ch, int xh, int bufi) {
        const ushort_t* src = sA + bufi*HBUF;
        short8 bf[8], bfn[8];
#pragma unroll
        for (int j = 0; j < 4; ++j)
#pragma unroll
            for (int k = 0; k < 2; ++k)
                bf[j*2+k] = *(const short8*)(Wpk +
                    (((size_t)(og*4+j)*54 + ch*2 + k)*64 + lane)*8);
#pragma unroll
        for (int tap = 0; tap < 9; ++tap) {
            if (tap < 8) {
#pragma unroll
                for (int j = 0; j < 4; ++j)
#pragma unroll
                    for (int k = 0; k < 2; ++k)
                        bfn[j*2+k] = *(const short8*)(Wpk +
                            (((size_t)(og*4+j)*54 + (tap+1)*6 + ch*2 + k)*64 + lane)*8);
            }
            const int ky = tap/3, kx = tap - ky*3;
            const int sw = (kx + m) & 7;
            const int rowb = ((yi + ky)*HGX + kx + m)*64;
            const int g0 = (quad ^ sw)*8, g1 = ((quad+4) ^ sw)*8;
#pragma unroll
            for (int xtl = 0; xtl < 4; ++xtl) {
                short8 af0 = *(const short8*)(src + rowb + xtl*1024 + g0);
                short8 af1 = *(const short8*)(src + rowb + xtl*1024 + g1);
                const int xa = xh*4 + xtl;
#pragma unroll
                for (int j = 0; j < 4; ++j) {
                    acc[j*8+xa] = __builtin_amdgcn_mfma_f32_16x16x32_bf16(af0, bf[j*2],   acc[j*8+xa], 0,0,0);
                    acc[j*8+xa] = __builtin_amdgcn_mfma_f32_16x16x32_bf16(af1, bf[j*2+1], acc[j*8+xa], 0,0,0);
                }
            }
#pragma unroll
            for (int q = 0; q < 8; ++q) bf[q] = bfn[q];
        }
    };

    // ---- pipeline: 6 half-stages (ch,xh), producers one stage ahead ----
    if (wv >= 6) produce(0, 0, 0);
    __syncthreads();
    for (int s = 0; s < 6; ++s) {
        if (wv >= 6) {
            if (s < 5) produce((s + 1) >> 1, (s + 1) & 1, (s + 1) & 1);
        } else {
            compute(s >> 1, s & 1, s & 1);
        }
        __syncthreads();
    }

    // ---- epilogue: BN+ReLU -> LDS stage (96 ch at a time) -> full lines ----
    float* sOut = (float*)sA;                  // 96 x 132 f32 = 50,688 B
    for (int y = 0; y < 2; ++y) {
        for (int oh = 0; oh < 2; ++oh) {
            if (wv < 6 && yi == y) {
#pragma unroll
                for (int j = 0; j < 4; ++j) {
                    int ot = og*4 + j;
                    if (ot >= oh*6 && ot < oh*6 + 6) {
                        int o = ot*16 + m;
                        float A  = gamma[o] * rsqrtf(var[o] + 1e-4f);
                        float Bv = (bias[o] - mean[o])*A + beta[o];
#pragma unroll
                        for (int xt = 0; xt < 8; ++xt) {
                            f32x4 a4 = acc[j*8 + xt];
                            *(float4*)(sOut + (o - oh*96)*132 + xt*16 + quad*4) =
                                make_float4(fmaxf(a4[0]*A + Bv, 0.f), fmaxf(a4[1]*A + Bv, 0.f),
                                            fmaxf(a4[2]*A + Bv, 0.f), fmaxf(a4[3]*A + Bv, 0.f));
                        }
                    }
                }
            }
            __syncthreads();
#pragma unroll
            for (int i = 0; i < 6; ++i) {
                int s = i*512 + t;             // 3072 float4 slots
                int ol = s >> 5, xs4 = (s & 31)*4;
                float4 v = *(const float4*)(sOut + ol*132 + xs4);
                *(float4*)(out + (((size_t)b*C3 + oh*96 + ol)*H + y0 + y)*WD + xs4) = v;
            }
            __syncthreads();
        }
    }
}

extern "C" void kernel_launch(void* const* d_in, const int* in_sizes, int n_in,
                              void* d_out, int out_size, void* d_ws, size_t ws_size,
                              hipStream_t stream)
{
    const float* x   = (const float*)d_in[0];
    const float* xf  = (const float*)d_in[1];
    const float* xr  = (const float*)d_in[2];
    const float* Wx  = (const float*)d_in[3];
    const float* bx  = (const float*)d_in[4];
    const float* Wx1 = (const float*)d_in[5];
    const float* bx1 = (const float*)d_in[6];
    const float* Wx2 = (const float*)d_in[7];
    const float* bx2 = (const float*)d_in[8];
    const float* Wxf = (const float*)d_in[9];
    const float* bxf = (const float*)d_in[10];
    const float* Wxr = (const float*)d_in[11];
    const float* bxr = (const float*)d_in[12];
    const float* Wm  = (const float*)d_in[13];
    const float* bms = (const float*)d_in[14];
    const float* gam = (const float*)d_in[15];
    const float* bet = (const float*)d_in[16];
    const float* mea = (const float*)d_in[17];
    const float* va  = (const float*)d_in[18];
    (void)in_sizes; (void)n_in; (void)out_size; (void)ws_size;

    // ws layout (bytes):
    //   feat (B,PW,PW,128) bf16 @ 0            (34,611,200)
    //   xcl  (B,PW,PW,64)  bf16 @ 34,611,200   (17,305,600)  -> ends 51,916,800
    //   Wpk  @ 51,916,800  (663,552)           -> ends 52,580,352
    //   Wall @ 52,700,000  (40,960); ball @ 52,750,000 (1,280)
    // xfT/xrT scratch live in d_out (fully overwritten by conv afterwards):
    //   xfT @ d_out+0 (16,777,216), xrT @ d_out+16,777,216 (16,777,216)
    ushort_t* feat = (ushort_t*)d_ws;
    ushort_t* xcl  = (ushort_t*)((char*)d_ws + 34611200);
    ushort_t* Wpk  = (ushort_t*)((char*)d_ws + 51916800);
    ushort_t* Wall = (ushort_t*)((char*)d_ws + 52700000);
    float*    ball = (float*)   ((char*)d_ws + 52750000);
    ushort_t* xfT  = (ushort_t*)d_out;
    ushort_t* xrT  = (ushort_t*)((char*)d_out + 16777216);
    float* outp = (float*)d_out;

    compose_kernel<<<dim3(64), dim3(64), 0, stream>>>(
        Wx, bx, Wx1, bx1, Wx2, bx2, Wxf, bxf, Wxr, bxr, Wall, ball);
    pack_kernel<<<dim3(162), dim3(256), 0, stream>>>(Wm, Wpk);
    prep_kernel<<<dim3(3*BATCH*PW), dim3(256), 0, stream>>>(
        x, xf, xr, xcl, feat, xfT, xrT);
    attn_mfma<<<dim3(BATCH*H), dim3(256), 0, stream>>>(
        xcl, xfT, xrT, Wall, ball, feat);
    conv_mfma<<<dim3(BATCH*64), dim3(512), 0, stream>>>(
        feat, xcl, Wpk, bms, gam, bet, mea, va, outp);
}

// Round 6
// 356.755 us; speedup vs baseline: 4.2127x; 4.2127x over previous
//
#include <hip/hip_runtime.h>

#define BATCH 8
#define C     64
#define H     128
#define WD    128
#define C3    192
#define HW    (H*WD)
#define PW    130         // padded H/W for conv input
#define CBUF  (4*PW*64)   // conv stage buffer: 4 rows x 130 gx x 64 c (shorts)

// attn LDS tiles: 64 rows x 64 cols, granule-XOR swizzled, no pad.
#define SWZ(r) ((((r) & 7) ^ (((r) >> 3) & 6)))

typedef __attribute__((ext_vector_type(8))) short short8;
typedef __attribute__((ext_vector_type(4))) float f32x4;
typedef unsigned short ushort_t;

__device__ __forceinline__ unsigned short f2bf(float f) {
    unsigned u = __builtin_bit_cast(unsigned, f);
    u += 0x7fffu + ((u >> 16) & 1u);
    return (unsigned short)(u >> 16);
}
__device__ __forceinline__ int pack2(unsigned short lo, unsigned short hi) {
    return (int)(((unsigned)hi << 16) | (unsigned)lo);
}

// ===========================================================================
// compose_kernel: fold Wx into Wx1/Wx2; pack 5 weight mats to bf16 + biases.
// ===========================================================================
__global__ __launch_bounds__(64) void compose_kernel(
    const float* __restrict__ Wx,  const float* __restrict__ bx,
    const float* __restrict__ Wx1, const float* __restrict__ bx1,
    const float* __restrict__ Wx2, const float* __restrict__ bx2,
    const float* __restrict__ Wxf, const float* __restrict__ bxf,
    const float* __restrict__ Wxr, const float* __restrict__ bxr,
    ushort_t* __restrict__ Wall, float* __restrict__ ball)
{
    int o = blockIdx.x;      // 0..63
    int c = threadIdx.x;     // 0..63
    Wall[0*4096 + o*64 + c] = f2bf(Wx [o*64 + c]);
    Wall[3*4096 + o*64 + c] = f2bf(Wxf[o*64 + c]);
    Wall[4*4096 + o*64 + c] = f2bf(Wxr[o*64 + c]);
    float a1 = 0.f, a2 = 0.f;
    for (int k = 0; k < 64; ++k) {
        float wc = Wx[k*64 + c];          // coalesced across lanes
        a1 += Wx1[o*64 + k] * wc;         // scalar broadcast
        a2 += Wx2[o*64 + k] * wc;
    }
    Wall[1*4096 + o*64 + c] = f2bf(a1);
    Wall[2*4096 + o*64 + c] = f2bf(a2);
    float t1 = Wx1[o*64 + c] * bx[c];
    float t2 = Wx2[o*64 + c] * bx[c];
    for (int off = 32; off; off >>= 1) {
        t1 += __shfl_down(t1, off);
        t2 += __shfl_down(t2, off);
    }
    if (c == 0) {
        ball[0*64 + o] = bx[o];
        ball[1*64 + o] = bx1[o] + t1;
        ball[2*64 + o] = bx2[o] + t2;
        ball[3*64 + o] = bxf[o];
        ball[4*64 + o] = bxr[o];
    }
}

// ===========================================================================
// prep v4: split into 3 independent block families (x / xf / xr).
// which=0 also zeroes feat+xcl halos.
// ===========================================================================
__global__ __launch_bounds__(256) void prep_kernel(
    const float* __restrict__ x, const float* __restrict__ xf,
    const float* __restrict__ xr,
    ushort_t* __restrict__ xcl, ushort_t* __restrict__ feat,
    ushort_t* __restrict__ xfT, ushort_t* __restrict__ xrT)
{
    const int which = blockIdx.x / (BATCH*PW);
    const int r = blockIdx.x % (BATCH*PW);
    const int b = r / PW, py = r % PW;
    const int t = threadIdx.x;
    const size_t prow = ((size_t)b*PW + py)*PW;   // pixel row base

    __shared__ ushort_t sx[128*72];

    if (which == 0) {
        if (py == 0 || py == PW-1) {
            int4 z = make_int4(0,0,0,0);
            for (int j = t; j < PW*128/8; j += 256) ((int4*)(feat + prow*128))[j] = z;
            for (int j = t; j < PW*64/8;  j += 256) ((int4*)(xcl  + prow*64 ))[j] = z;
            return;
        }
        if (t < 48) {
            int4 z = make_int4(0,0,0,0);
            if (t < 32) {
                int side = t >> 4, seg = t & 15;
                *(int4*)(feat + (prow + (side ? PW-1 : 0))*128 + seg*8) = z;
            } else {
                int u = t - 32, side = u >> 3, seg = u & 7;
                *(int4*)(xcl + (prow + (side ? PW-1 : 0))*64 + seg*8) = z;
            }
        }
        const int y = py - 1;
        for (int k = t; k < 64*128; k += 256) {
            int c = k >> 7, xx = k & 127;
            sx[xx*72 + c] = f2bf(x[((size_t)b*C + c)*HW + (size_t)y*WD + xx]);
        }
        __syncthreads();
        for (int j = t; j < 128*8; j += 256) {
            int xx = j >> 3, seg = j & 7;
            *(int4*)(xcl + (prow + xx + 1)*64 + seg*8) = *(const int4*)(sx + xx*72 + seg*8);
        }
        return;
    }

    if (py == 0 || py == PW-1) return;
    const int y = py - 1;
    const float* src = (which == 1) ? xf : xr;
    ushort_t* dstT   = (which == 1) ? xfT : xrT;
    for (int k = t; k < 64*128; k += 256) {
        int c = k >> 7, xx = k & 127;
        sx[xx*72 + c] = f2bf(src[((size_t)b*C + c)*HW + (size_t)y*WD + xx]);
    }
    __syncthreads();
    for (int j = t; j < 128*8; j += 256) {
        int xx = j >> 3, seg = j & 7;
        *(int4*)(dstT + (((size_t)b*128 + y)*128 + xx)*64 + seg*8) = *(const int4*)(sx + xx*72 + seg*8);
    }
}

// ===========================================================================
// attn_mfma v3: one block per (b,h), 256 threads = 4 waves. (unchanged)
// ===========================================================================
__global__ __launch_bounds__(256, 3) void attn_mfma(
    const ushort_t* __restrict__ xcl, const ushort_t* __restrict__ xfT,
    const ushort_t* __restrict__ xrT,
    const ushort_t* __restrict__ Wall, const float* __restrict__ ball,
    ushort_t* __restrict__ feat)
{
    __shared__ ushort_t lds[6*4096];
    ushort_t* P = lds;            // buffer roles rotate; see phase comments
    ushort_t* Q = lds + 4096;
    ushort_t* U = lds + 2*4096;
    ushort_t* R = lds + 3*4096;
    ushort_t* V = lds + 4*4096;
    ushort_t* T = lds + 5*4096;

    const int t = threadIdx.x;
    const int wv = t >> 6, lane = t & 63, m = lane & 15, quad = lane >> 4;
    const int b = blockIdx.x >> 7, h = blockIdx.x & 127;
    const size_t rowbase = ((size_t)b*PW + h + 1)*PW;          // xcl/feat pixels
    const ushort_t* xrow  = xcl + (rowbase + 1)*64;            // interior pixel 0
    const ushort_t* xfrow = xfT + ((size_t)b*128 + h)*128*64;
    const ushort_t* xrrow = xrT + ((size_t)b*128 + h)*128*64;

    // stage a 64-pixel x 64-ch bf16 tile (pixel stride 64 shorts) into LDS
    auto stageT = [&](const ushort_t* base, ushort_t* dst) {
#pragma unroll
        for (int it = 0; it < 2; ++it) {
            int slot = it*256 + t;               // 512 slots of 16B
            int w = slot >> 3, seg = slot & 7;
            *(int4*)(dst + w*64 + ((seg ^ SWZ(w)) << 3)) =
                *(const int4*)(base + w*64 + seg*8);
        }
    };
    auto projB = [&](const ushort_t* src, const ushort_t* W, const float* bias,
                     ushort_t* dst) {
        int arow = wv*16 + m;
        int sa = SWZ(arow);
#pragma unroll
        for (int nt = 0; nt < 4; ++nt) {
            f32x4 acc = {0.f,0.f,0.f,0.f};
#pragma unroll
            for (int k = 0; k < 2; ++k) {
                short8 a  = *(const short8*)(src + arow*64 + (((4*k+quad) ^ sa) << 3));
                short8 bb = *(const short8*)(W   + (nt*16 + m)*64  + k*32 + quad*8);
                acc = __builtin_amdgcn_mfma_f32_16x16x32_bf16(a, bb, acc, 0,0,0);
            }
            float bo = bias[nt*16 + m];
            int o = nt*16 + m, w0 = wv*16 + quad*4;
            int base = o*64 + (((w0 >> 3) ^ SWZ(o)) << 3) + (w0 & 7);
            *(int*)(dst + base)     = pack2(f2bf(acc[0]+bo), f2bf(acc[1]+bo));
            *(int*)(dst + base + 2) = pack2(f2bf(acc[2]+bo), f2bf(acc[3]+bo));
        }
    };
    auto projA = [&](const ushort_t* src, const ushort_t* W, const float* bias,
                     ushort_t* dstT) {
        float b4[4];
#pragma unroll
        for (int r = 0; r < 4; ++r) b4[r] = bias[wv*16 + quad*4 + r];
#pragma unroll
        for (int nt = 0; nt < 4; ++nt) {
            f32x4 acc = {0.f,0.f,0.f,0.f};
            int brow = nt*16 + m;
            int sb = SWZ(brow);
#pragma unroll
            for (int k = 0; k < 2; ++k) {
                short8 a  = *(const short8*)(W   + (wv*16 + m)*64  + k*32 + quad*8);
                short8 bb = *(const short8*)(src + brow*64 + (((4*k+quad) ^ sb) << 3));
                acc = __builtin_amdgcn_mfma_f32_16x16x32_bf16(a, bb, acc, 0,0,0);
            }
            int w = nt*16 + m, o0 = wv*16 + quad*4;
            int base = w*64 + (((o0 >> 3) ^ SWZ(w)) << 3) + (o0 & 7);
            *(int*)(dstT + base)     = pack2(f2bf(acc[0]+b4[0]), f2bf(acc[1]+b4[1]));
            *(int*)(dstT + base + 2) = pack2(f2bf(acc[2]+b4[2]), f2bf(acc[3]+b4[3]));
        }
    };
    auto scoreStep = [&](const ushort_t* A, const ushort_t* B, f32x4* sc) {
        int arow = wv*16 + m;
        int sa = SWZ(arow);
#pragma unroll
        for (int nt = 0; nt < 4; ++nt) {
            int brow = nt*16 + m;
            int sb = SWZ(brow);
#pragma unroll
            for (int k = 0; k < 2; ++k) {
                short8 a  = *(const short8*)(A + arow*64 + (((4*k+quad) ^ sa) << 3));
                short8 bb = *(const short8*)(B + brow*64 + (((4*k+quad) ^ sb) << 3));
                sc[nt] = __builtin_amdgcn_mfma_f32_16x16x32_bf16(a, bb, sc[nt], 0,0,0);
            }
        }
    };
    auto scoreDump = [&](const f32x4* sc, ushort_t* dst) {
        int c0 = wv*16 + quad*4;
#pragma unroll
        for (int nt = 0; nt < 4; ++nt) {
            int d = nt*16 + m;
            int gd = d >> 3, dl = d & 7;
#pragma unroll
            for (int r = 0; r < 4; ++r) {
                int row = c0 + r;
                dst[row*64 + ((gd ^ SWZ(row)) << 3) + dl] = f2bf(sc[nt][r]);
            }
        }
    };
    auto featF = [&](const ushort_t* Sc, const ushort_t* XpT, ushort_t* stg) {
        int arow = wv*16 + m;
        int sa = SWZ(arow);
#pragma unroll
        for (int nt = 0; nt < 4; ++nt) {
            f32x4 acc = {0.f,0.f,0.f,0.f};
            int brow = nt*16 + m;
            int sb = SWZ(brow);
#pragma unroll
            for (int k = 0; k < 2; ++k) {
                short8 a  = *(const short8*)(Sc  + arow*64 + (((4*k+quad) ^ sa) << 3));
                short8 bb = *(const short8*)(XpT + brow*64 + (((4*k+quad) ^ sb) << 3));
                acc = __builtin_amdgcn_mfma_f32_16x16x32_bf16(a, bb, acc, 0,0,0);
            }
            int w = nt*16 + m, c0 = wv*16 + quad*4;
            int base = w*64 + (((c0 >> 3) ^ SWZ(w)) << 3) + (c0 & 7);
            *(int*)(stg + base)     = pack2(f2bf(acc[0]), f2bf(acc[1]));
            *(int*)(stg + base + 2) = pack2(f2bf(acc[2]), f2bf(acc[3]));
        }
    };
    auto emitPair = [&](const ushort_t* O1, const ushort_t* O2, int wc) {
#pragma unroll
        for (int it = 0; it < 4; ++it) {
            int j = (it & 1)*256 + t;
            const ushort_t* S = (it < 2) ? O1 : O2;
            int half = (it < 2) ? 0 : 64;
            int row = j >> 3, seg = j & 7;
            int4 v = *(const int4*)(S + row*64 + ((seg ^ SWZ(row)) << 3));
            *(int4*)(feat + (rowbase + wc + 1 + row)*128 + half + seg*8) = v;
        }
    };

    const ushort_t* W0 = Wall;            const float* b0 = ball;
    const ushort_t* W1 = Wall + 4096;     const float* b1 = ball + 64;
    const ushort_t* W2 = Wall + 2*4096;   const float* b2 = ball + 128;
    const ushort_t* W3 = Wall + 3*4096;   const float* b3 = ball + 192;
    const ushort_t* W4 = Wall + 4*4096;   const float* b4 = ball + 256;

    f32x4 sc1[4], sc2[4];
#pragma unroll
    for (int i = 0; i < 4; ++i) { sc1[i] = (f32x4){0,0,0,0}; sc2[i] = (f32x4){0,0,0,0}; }

    // ================= loop 1: scores (3 phases/chunk) =================
    stageT(xrow, P); stageT(xfrow, Q); stageT(xrrow, U);
    __syncthreads();
    // chunk 0: x=P, xf=Q, xr=U
    projB(P, W1, b1, R);  projB(P, W2, b2, V);  projB(Q, W3, b3, T);
    __syncthreads();
    scoreStep(R, T, sc1); projB(U, W4, b4, Q);
    __syncthreads();
    scoreStep(V, Q, sc2);
    stageT(xrow + 64*64, P); stageT(xfrow + 64*64, T); stageT(xrrow + 64*64, U);
    __syncthreads();
    // chunk 1: x=P, xf=T, xr=U
    projB(P, W1, b1, R);  projB(P, W2, b2, V);  projB(T, W3, b3, Q);
    __syncthreads();
    scoreStep(R, Q, sc1); projB(U, W4, b4, T);
    __syncthreads();
    scoreStep(V, T, sc2);
    stageT(xrow, P);                       // x chunk0 again for loop 2
    __syncthreads();

    // ================= loop 2: features (3 phases/chunk) =================
    scoreDump(sc1, Q);  scoreDump(sc2, U);
    __syncthreads();
    // chunk 0: X=P -> XT=R; outputs P,T; prefetch x64 -> V
    projA(P, W0, b0, R);
    __syncthreads();
    featF(Q, R, P);  featF(U, R, T);  stageT(xrow + 64*64, V);
    __syncthreads();
    emitPair(P, T, 0);
    __syncthreads();
    // chunk 1: X=V -> XT=R; outputs V,T
    projA(V, W0, b0, R);
    __syncthreads();
    featF(Q, R, V);  featF(U, R, T);
    __syncthreads();
    emitPair(V, T, 64);
}

// ===========================================================================
// weight pack for conv: W_msa -> Wpack[otile][tap*6+icc][lane][8] bf16.
// ===========================================================================
__global__ __launch_bounds__(256) void pack_kernel(const float* __restrict__ W,
                                                   ushort_t* __restrict__ Wpk)
{
    int k = blockIdx.x*256 + threadIdx.x;
    if (k >= 12*54*64) return;
    int lane = k & 63, os = k >> 6;
    int otile = os / 54, s = os % 54;
    int tap = s / 6, icc = s % 6;
    int o   = otile*16 + (lane & 15);
    int ic0 = icc*32 + (lane >> 4)*8;
    ushort_t v[8];
#pragma unroll
    for (int j = 0; j < 8; ++j)
        v[j] = f2bf(W[(size_t)(o*C3 + ic0 + j)*9 + tap]);
    *(int4*)(Wpk + (size_t)k*8) = *(const int4*)v;
}

// ===========================================================================
// conv v7: uniform 8-wave implicit-GEMM bf16 MFMA (v4 geometry, no parked
// producers). Block = (b, y-pair), 512 threads = 8 waves; every wave stages
// chunk ch+1 (global_load_lds) then computes chunk ch. Wave (yi, og):
// yi=wv&1 row, og=wv>>1 owns 3 o-tiles x 8 xt -> acc[24] f32x4 = 96 regs,
// all statically indexed (rule #20). launch_bounds(512,2) -> 256-reg cap,
// no spill. Same LDS layout/swizzle/K-order as v4 -> bit-identical output.
// SIMD balance: 2 compute waves per SIMD (v4 was 2/2/1/1 + 2 parked).
// ===========================================================================
__global__ __launch_bounds__(512, 2) void conv_mfma(
    const ushort_t* __restrict__ feat, const ushort_t* __restrict__ xcl,
    const ushort_t* __restrict__ Wpk,
    const float* __restrict__ bias, const float* __restrict__ gamma,
    const float* __restrict__ beta, const float* __restrict__ mean,
    const float* __restrict__ var,  float* __restrict__ out)
{
    __shared__ ushort_t sA[2*CBUF];            // 133,120 B

    const int t = threadIdx.x;
    const int wv = t >> 6, lane = t & 63;
    const int m = lane & 15, quad = lane >> 4;
    const int b  = blockIdx.x >> 6, y0 = (blockIdx.x & 63)*2;
    const int yi = wv & 1, og = wv >> 1;       // og 0..3: otiles og*3+j (j<3)

    f32x4 acc[24];                              // [j][xt] -> acc[j*8+xt]
#pragma unroll
    for (int i = 0; i < 24; ++i) acc[i] = (f32x4){0.f,0.f,0.f,0.f};

    // ---- stage one 64-c chunk (4160 16B slots) across all 512 threads ----
    auto stageAll = [&](int ch, int bufi) {
        ushort_t* dst = sA + bufi*CBUF;
        const ushort_t* base = (ch < 2) ? feat : xcl;
        const int ps = (ch < 2) ? 128 : 64;
        const int co = (ch == 1) ? 64 : 0;
#pragma unroll
        for (int i = 0; i < 8; ++i) {
            int sl = i*512 + t;
            int wi = sl & 7, rowgx = sl >> 3;
            int row = rowgx / PW, gx = rowgx - row*PW;
            int wl = wi ^ (gx & 7);            // granule swizzle (global side)
            const ushort_t* g = base + (((size_t)b*PW + y0 + row)*PW + gx)*ps
                                     + co + wl*8;
            __builtin_amdgcn_global_load_lds(
                (const __attribute__((address_space(1))) unsigned int*)g,
                (__attribute__((address_space(3))) unsigned int*)(dst + (size_t)sl*8),
                16, 0, 0);
        }
        if (t < 64) {
            int sl = 4096 + t;
            int wi = sl & 7, rowgx = sl >> 3;
            int row = rowgx / PW, gx = rowgx - row*PW;
            int wl = wi ^ (gx & 7);
            const ushort_t* g = base + (((size_t)b*PW + y0 + row)*PW + gx)*ps
                                     + co + wl*8;
            __builtin_amdgcn_global_load_lds(
                (const __attribute__((address_space(1))) unsigned int*)g,
                (__attribute__((address_space(3))) unsigned int*)(dst + (size_t)sl*8),
                16, 0, 0);
        }
    };

    // ---- consumer: one 64-c chunk = 9 taps x 8 xt x 2 k x 3 o-tiles ----
    auto compute = [&](int ch, int bufi) {
        const ushort_t* src = sA + bufi*CBUF;
        short8 bf[6], bfn[6];
#pragma unroll
        for (int j = 0; j < 3; ++j)
#pragma unroll
            for (int k = 0; k < 2; ++k)
                bf[j*2+k] = *(const short8*)(Wpk +
                    (((size_t)(og*3+j)*54 + ch*2 + k)*64 + lane)*8);
#pragma unroll
        for (int tap = 0; tap < 9; ++tap) {
            if (tap < 8) {
#pragma unroll
                for (int j = 0; j < 3; ++j)
#pragma unroll
                    for (int k = 0; k < 2; ++k)
                        bfn[j*2+k] = *(const short8*)(Wpk +
                            (((size_t)(og*3+j)*54 + (tap+1)*6 + ch*2 + k)*64 + lane)*8);
            }
            const int ky = tap/3, kx = tap - ky*3;
            const int sw = (kx + m) & 7;
            const int rowb = ((yi + ky)*PW + kx + m)*64;
            const int g0 = (quad ^ sw)*8, g1 = ((quad+4) ^ sw)*8;
#pragma unroll
            for (int xt = 0; xt < 8; ++xt) {
                short8 af0 = *(const short8*)(src + rowb + xt*1024 + g0);
                short8 af1 = *(const short8*)(src + rowb + xt*1024 + g1);
#pragma unroll
                for (int j = 0; j < 3; ++j) {
                    acc[j*8+xt] = __builtin_amdgcn_mfma_f32_16x16x32_bf16(af0, bf[j*2],   acc[j*8+xt], 0,0,0);
                    acc[j*8+xt] = __builtin_amdgcn_mfma_f32_16x16x32_bf16(af1, bf[j*2+1], acc[j*8+xt], 0,0,0);
                }
            }
#pragma unroll
            for (int q = 0; q < 6; ++q) bf[q] = bfn[q];
        }
    };

    // ---- pipeline: 3 chunks of 64 c; all waves stage next, compute cur ----
    stageAll(0, 0);
    __syncthreads();
    for (int ch = 0; ch < 3; ++ch) {
        if (ch < 2) stageAll(ch + 1, (ch + 1) & 1);
        compute(ch, ch & 1);
        __syncthreads();                       // per-wave vmcnt drain + barrier
    }

    // ---- epilogue: BN+ReLU -> LDS stage -> full-line stores ----
    float* sOut = (float*)sA;                  // 192 x 132 f32 = 101,376 B
    for (int y = 0; y < 2; ++y) {
        if (yi == y) {
#pragma unroll
            for (int j = 0; j < 3; ++j) {
                int o = (og*3 + j)*16 + m;
                float A  = gamma[o] * rsqrtf(var[o] + 1e-4f);
                float Bv = (bias[o] - mean[o])*A + beta[o];
#pragma unroll
                for (int xt = 0; xt < 8; ++xt) {
                    f32x4 a4 = acc[j*8 + xt];
                    *(float4*)(sOut + o*132 + xt*16 + quad*4) =
                        make_float4(fmaxf(a4[0]*A + Bv, 0.f), fmaxf(a4[1]*A + Bv, 0.f),
                                    fmaxf(a4[2]*A + Bv, 0.f), fmaxf(a4[3]*A + Bv, 0.f));
                }
            }
        }
        __syncthreads();
#pragma unroll
        for (int i = 0; i < 12; ++i) {
            int s = i*512 + t;                 // 6144 float4 slots
            int o = s >> 5, xs4 = (s & 31)*4;
            float4 v = *(const float4*)(sOut + o*132 + xs4);
            *(float4*)(out + (((size_t)b*C3 + o)*H + y0 + y)*WD + xs4) = v;
        }
        __syncthreads();
    }
}

extern "C" void kernel_launch(void* const* d_in, const int* in_sizes, int n_in,
                              void* d_out, int out_size, void* d_ws, size_t ws_size,
                              hipStream_t stream)
{
    const float* x   = (const float*)d_in[0];
    const float* xf  = (const float*)d_in[1];
    const float* xr  = (const float*)d_in[2];
    const float* Wx  = (const float*)d_in[3];
    const float* bx  = (const float*)d_in[4];
    const float* Wx1 = (const float*)d_in[5];
    const float* bx1 = (const float*)d_in[6];
    const float* Wx2 = (const float*)d_in[7];
    const float* bx2 = (const float*)d_in[8];
    const float* Wxf = (const float*)d_in[9];
    const float* bxf = (const float*)d_in[10];
    const float* Wxr = (const float*)d_in[11];
    const float* bxr = (const float*)d_in[12];
    const float* Wm  = (const float*)d_in[13];
    const float* bms = (const float*)d_in[14];
    const float* gam = (const float*)d_in[15];
    const float* bet = (const float*)d_in[16];
    const float* mea = (const float*)d_in[17];
    const float* va  = (const float*)d_in[18];
    (void)in_sizes; (void)n_in; (void)out_size; (void)ws_size;

    // ws layout (bytes):
    //   feat (B,PW,PW,128) bf16 @ 0            (34,611,200)
    //   xcl  (B,PW,PW,64)  bf16 @ 34,611,200   (17,305,600)  -> ends 51,916,800
    //   Wpk  @ 51,916,800  (663,552)           -> ends 52,580,352
    //   Wall @ 52,700,000  (40,960); ball @ 52,750,000 (1,280)
    // xfT/xrT scratch live in d_out (fully overwritten by conv afterwards):
    //   xfT @ d_out+0 (16,777,216), xrT @ d_out+16,777,216 (16,777,216)
    ushort_t* feat = (ushort_t*)d_ws;
    ushort_t* xcl  = (ushort_t*)((char*)d_ws + 34611200);
    ushort_t* Wpk  = (ushort_t*)((char*)d_ws + 51916800);
    ushort_t* Wall = (ushort_t*)((char*)d_ws + 52700000);
    float*    ball = (float*)   ((char*)d_ws + 52750000);
    ushort_t* xfT  = (ushort_t*)d_out;
    ushort_t* xrT  = (ushort_t*)((char*)d_out + 16777216);
    float* outp = (float*)d_out;

    compose_kernel<<<dim3(64), dim3(64), 0, stream>>>(
        Wx, bx, Wx1, bx1, Wx2, bx2, Wxf, bxf, Wxr, bxr, Wall, ball);
    pack_kernel<<<dim3(162), dim3(256), 0, stream>>>(Wm, Wpk);
    prep_kernel<<<dim3(3*BATCH*PW), dim3(256), 0, stream>>>(
        x, xf, xr, xcl, feat, xfT, xrT);
    attn_mfma<<<dim3(BATCH*H), dim3(256), 0, stream>>>(
        xcl, xfT, xrT, Wall, ball, feat);
    conv_mfma<<<dim3(BATCH*64), dim3(512), 0, stream>>>(
        feat, xcl, Wpk, bms, gam, bet, mea, va, outp);
}